// Round 13
// baseline (319.817 us; speedup 1.0000x reference)
//
#include <hip/hip_runtime.h>
#include <hip/hip_bf16.h>
#include <cmath>

// Problem dims (fixed by reference): B=2, T=2048, C=1024, H=16, D=64
// Inputs fp32, output fp32.
#define TB   2048
#define CCH  1024
#define NCH  32      // chunks per (b,h): T / 64
#define EPSF 1e-6f

typedef unsigned short u16;
typedef __attribute__((ext_vector_type(8))) short  frag8;   // 8 bf16 (4 VGPRs)
typedef __attribute__((ext_vector_type(4))) float  floatx4; // MFMA C/D

// RNE float -> bf16 (finite inputs only)
__device__ __forceinline__ u16 f2bf(float f) {
    unsigned int u = __float_as_uint(f);
    unsigned int r = (u + 0x7fffu + ((u >> 16) & 1u)) >> 16;
    return (u16)r;
}
__device__ __forceinline__ float bf2f(u16 v) {
    return __uint_as_float(((unsigned int)v) << 16);
}

// Async global->LDS, 16 B per lane (wave-uniform base + lane*16; unpadded dest).
__device__ __forceinline__ void async_load16(const u16* g, u16* l) {
    __builtin_amdgcn_global_load_lds(
        (const __attribute__((address_space(1))) void*)g,
        (__attribute__((address_space(3))) void*)l,
        16, 0, 0);
}

// ---------------------------------------------------------------------------
// Fused prep: [0,2048) cvt x->bf16 ; [2048,2816) transpose w_attn ; rest w_proj.
// ---------------------------------------------------------------------------
__global__ __launch_bounds__(256) void prep_k(
    const float* __restrict__ x, const float* __restrict__ wa,
    const float* __restrict__ wp,
    u16* __restrict__ xb, u16* __restrict__ waT, u16* __restrict__ wpT)
{
    __shared__ u16 t[64][72];   // t[n][k]
    int blk = blockIdx.x;
    if (blk < 2048) {                       // cvt: 4096*1024 elems, 8/thread
        int i = (blk * 256 + threadIdx.x) * 8;
        float4 a = *(const float4*)(x + i);
        float4 b = *(const float4*)(x + i + 4);
        u16 v[8];
        v[0] = f2bf(a.x); v[1] = f2bf(a.y); v[2] = f2bf(a.z); v[3] = f2bf(a.w);
        v[4] = f2bf(b.x); v[5] = f2bf(b.y); v[6] = f2bf(b.z); v[7] = f2bf(b.w);
        *(uint4*)(xb + i) = *(uint4*)v;
        return;
    }
    const float* in; u16* out; int K, N, bx, by;
    if (blk < 2048 + 768) {                 // w_attn^T: (1024 x 3072) -> (3072 x 1024)
        int tb = blk - 2048; in = wa; out = waT; K = 1024; N = 3072;
        bx = tb % 48; by = tb / 48;
    } else {                                // w_proj^T: (1024 x 1024)
        int tb = blk - 2816; in = wp; out = wpT; K = 1024; N = 1024;
        bx = tb & 15; by = tb >> 4;
    }
    const int k0 = by * 64, n0 = bx * 64;
    #pragma unroll
    for (int i = 0; i < 4; ++i) {
        int rr = (threadIdx.x >> 4) + 16 * i;          // k-row
        int c4 = (threadIdx.x & 15) * 4;               // n-col
        float4 v = *(const float4*)(in + (size_t)(k0 + rr) * N + n0 + c4);
        t[c4 + 0][rr] = f2bf(v.x);
        t[c4 + 1][rr] = f2bf(v.y);
        t[c4 + 2][rr] = f2bf(v.z);
        t[c4 + 3][rr] = f2bf(v.w);
    }
    __syncthreads();
    #pragma unroll
    for (int i = 0; i < 2; ++i) {
        int rr = (threadIdx.x >> 3) + 32 * i;          // n-row
        int c8 = (threadIdx.x & 7) * 8;                // k-chunk
        u16 o[8];
        #pragma unroll
        for (int q = 0; q < 8; ++q) o[q] = t[rr][c8 + q];
        *(uint4*)(out + (size_t)(n0 + rr) * K + k0 + c8) = *(uint4*)o;
    }
}

// ---------------------------------------------------------------------------
// GEMM1: qkv(bf16) = phi(x @ w_attn), phi on cols < phi_cols.
// m97 pattern + XOR chunk swizzle (verified conflict-free, round 8).
// ---------------------------------------------------------------------------
__global__ __launch_bounds__(256) void gemm_bf16_bf16out_k(
    const u16* __restrict__ A, const u16* __restrict__ BT,
    u16* __restrict__ C, int N, int K, int phi_cols)
{
    __shared__ u16 Als[128 * 64];
    __shared__ u16 Bls[128 * 64];
    const int tid  = threadIdx.x;
    const int wave = tid >> 6, lane = tid & 63;
    const int quad = lane >> 4, lrow = lane & 15;
    const int wm = wave >> 1, wn = wave & 1;
    const int row0 = blockIdx.y * 128, col0 = blockIdx.x * 128;
    const int lr = lane >> 3;
    const int lc = ((lane & 7) ^ lr) * 8;
    const int rsw = lrow & 7;
    floatx4 acc[4][4] = {};

    for (int k0 = 0; k0 < K; k0 += 64) {
        __syncthreads();
        #pragma unroll
        for (int m = 0; m < 4; ++m) {
            int i = wave * 4 + m;
            async_load16(A  + (size_t)(row0 + i * 8 + lr) * K + k0 + lc, &Als[i * 512]);
            async_load16(BT + (size_t)(col0 + i * 8 + lr) * K + k0 + lc, &Bls[i * 512]);
        }
        __syncthreads();
        #pragma unroll
        for (int ksi = 0; ksi < 2; ++ksi) {
            frag8 af[4], bf[4];
            #pragma unroll
            for (int i = 0; i < 4; ++i)
                af[i] = *(const frag8*)&Als[(wm * 64 + i * 16 + lrow) * 64
                                            + ((ksi * 4 + quad) ^ rsw) * 8];
            #pragma unroll
            for (int i = 0; i < 4; ++i)
                bf[i] = *(const frag8*)&Bls[(wn * 64 + i * 16 + lrow) * 64
                                            + ((ksi * 4 + quad) ^ rsw) * 8];
            #pragma unroll
            for (int i = 0; i < 4; ++i)
                #pragma unroll
                for (int jn = 0; jn < 4; ++jn)
                    acc[i][jn] = __builtin_amdgcn_mfma_f32_16x16x32_bf16(
                        af[i], bf[jn], acc[i][jn], 0, 0, 0);
        }
    }

    #pragma unroll
    for (int i = 0; i < 4; ++i) {
        #pragma unroll
        for (int jn = 0; jn < 4; ++jn) {
            int col = col0 + wn * 64 + jn * 16 + lrow;
            bool isphi = col < phi_cols;
            #pragma unroll
            for (int r = 0; r < 4; ++r) {
                int row = row0 + wm * 64 + i * 16 + quad * 4 + r;
                float v = acc[i][jn][r];
                if (isphi) v = (v > 0.f) ? (v + 1.f) : __expf(v);  // phi = elu+1
                C[(size_t)row * N + col] = f2bf(v);
            }
        }
    }
}

// ---------------------------------------------------------------------------
// GEMM2: out(fp32) = Y @ w_proj. 128x64 tile, BK=128, 16-chunk XOR swizzle.
// ---------------------------------------------------------------------------
__global__ __launch_bounds__(256) void gemm_bf16_f32out_k(
    const u16* __restrict__ A, const u16* __restrict__ BT,
    float* __restrict__ C, int N, int K)
{
    __shared__ u16 Als[128 * 128];
    __shared__ u16 Bls[64 * 128];
    const int tid  = threadIdx.x;
    const int wave = tid >> 6, lane = tid & 63;
    const int quad = lane >> 4, lrow = lane & 15;
    const int wm = wave >> 1, wn = wave & 1;
    const int row0 = blockIdx.y * 128, col0 = blockIdx.x * 64;
    const int lr4 = lane >> 4;
    floatx4 acc[4][2] = {};

    for (int k0 = 0; k0 < K; k0 += 128) {
        __syncthreads();
        #pragma unroll
        for (int m = 0; m < 8; ++m) {
            int rbase = wave * 32 + m * 4;
            int cg = (lane & 15) ^ ((rbase + lr4) & 15);
            async_load16(A + (size_t)(row0 + rbase + lr4) * K + k0 + cg * 8,
                         &Als[rbase * 128]);
        }
        #pragma unroll
        for (int m = 0; m < 4; ++m) {
            int rbase = wave * 16 + m * 4;
            int cg = (lane & 15) ^ ((rbase + lr4) & 15);
            async_load16(BT + (size_t)(col0 + rbase + lr4) * K + k0 + cg * 8,
                         &Bls[rbase * 128]);
        }
        __syncthreads();
        #pragma unroll
        for (int ksi = 0; ksi < 4; ++ksi) {
            frag8 af[4], bf[2];
            #pragma unroll
            for (int i = 0; i < 4; ++i)
                af[i] = *(const frag8*)&Als[(wm * 64 + i * 16 + lrow) * 128
                                            + ((ksi * 4 + quad) ^ lrow) * 8];
            #pragma unroll
            for (int jn = 0; jn < 2; ++jn)
                bf[jn] = *(const frag8*)&Bls[(wn * 32 + jn * 16 + lrow) * 128
                                             + ((ksi * 4 + quad) ^ lrow) * 8];
            #pragma unroll
            for (int i = 0; i < 4; ++i)
                #pragma unroll
                for (int jn = 0; jn < 2; ++jn)
                    acc[i][jn] = __builtin_amdgcn_mfma_f32_16x16x32_bf16(
                        af[i], bf[jn], acc[i][jn], 0, 0, 0);
        }
    }

    #pragma unroll
    for (int i = 0; i < 4; ++i)
        #pragma unroll
        for (int jn = 0; jn < 2; ++jn) {
            int col = col0 + wn * 32 + jn * 16 + lrow;
            #pragma unroll
            for (int r = 0; r < 4; ++r) {
                int row = row0 + wm * 64 + i * 16 + quad * 4 + r;
                C[(size_t)row * N + col] = acc[i][jn][r];
            }
        }
}

// ---------------------------------------------------------------------------
// chunk_kv (MFMA): S_c^T = V^T K (bf16 [j][i]); z_c = colsum K; V^T exported
// to VtG for attn's async staging. Ticket tail: last block per (b,h) performs
// that bh's exclusive prefix scan (replaces the scan_state dispatch).
// Grid 1024 blocks ((b*16+h)*32+c), 256 threads = 4 waves.
// ---------------------------------------------------------------------------
__global__ __launch_bounds__(256) void chunk_kv_mfma_k(
    const u16* __restrict__ qkv,
    u16* __restrict__ Spt,
    float* __restrict__ zloc,
    u16* __restrict__ VtG,
    unsigned int* __restrict__ tickets)
{
    __shared__ u16 Kt[64][72];   // K^T [d][s]
    __shared__ u16 Vt[64][72];   // V^T [j][s]
    __shared__ unsigned int s_old;
    const int tid  = threadIdx.x;
    const int wave = tid >> 6, lane = tid & 63;
    const int quad = lane >> 4, lrow = lane & 15;
    const int blk = blockIdx.x;
    const int c = blk & 31, h = (blk >> 5) & 15, b = blk >> 9;
    const int t0 = c * 64;
    const u16* base = qkv + (size_t)(b * TB + t0) * 3072 + h * 64;

    #pragma unroll
    for (int m = 0; m < 2; ++m) {
        int chunk = tid + 256 * m;
        int s = chunk >> 3, d0 = (chunk & 7) * 8;
        const u16* row = base + (size_t)s * 3072;
        u16 kv[8], vv[8];
        *(uint4*)kv = *(const uint4*)(row + 1024 + d0);
        *(uint4*)vv = *(const uint4*)(row + 2048 + d0);
        #pragma unroll
        for (int q = 0; q < 8; ++q) { Kt[d0 + q][s] = kv[q]; Vt[d0 + q][s] = vv[q]; }
    }
    __syncthreads();

    // export V^T (row-major [j][s]) for attn's async staging
    #pragma unroll
    for (int m = 0; m < 2; ++m) {
        int e = tid + 256 * m;
        int r = e >> 3, c8 = (e & 7) * 8;
        u16 o[8];
        #pragma unroll
        for (int q = 0; q < 8; ++q) o[q] = Vt[r][c8 + q];
        *(uint4*)(VtG + (size_t)blk * 4096 + r * 64 + c8) = *(uint4*)o;
    }

    frag8 vf[2];
    #pragma unroll
    for (int ks = 0; ks < 2; ++ks)
        vf[ks] = *(const frag8*)&Vt[wave * 16 + lrow][ks * 32 + quad * 8];
    u16* So = Spt + (size_t)blk * 4096;
    #pragma unroll
    for (int jn = 0; jn < 4; ++jn) {
        floatx4 acc = {};
        #pragma unroll
        for (int ks = 0; ks < 2; ++ks) {
            frag8 kf = *(const frag8*)&Kt[jn * 16 + lrow][ks * 32 + quad * 8];
            acc = __builtin_amdgcn_mfma_f32_16x16x32_bf16(vf[ks], kf, acc, 0, 0, 0);
        }
        #pragma unroll
        for (int r = 0; r < 4; ++r) {
            int j = wave * 16 + quad * 4 + r;     // row of S^T
            int i = jn * 16 + lrow;               // col of S^T
            So[j * 64 + i] = f2bf(acc[r]);
        }
    }
    if (tid < 64) {
        float z = 0.f;
        for (int s = 0; s < 64; ++s) z += bf2f(Kt[tid][s]);
        zloc[(size_t)blk * 64 + tid] = z;
    }

    // ---- ticket: last block of this bh performs the prefix scan ----
    __threadfence();           // release this block's Spt/zloc writes
    __syncthreads();
    if (tid == 0) s_old = atomicAdd(&tickets[blk >> 5], 1u);
    __syncthreads();
    if (s_old == 31u) {
        __threadfence();       // acquire all 32 blocks' writes
        const int bh = blk >> 5;
        const size_t sbase = (size_t)bh * NCH * 4096;
        float r0[8] = {}, r1[8] = {};
        for (int cc = 0; cc < NCH; ++cc) {
            u16* p0 = Spt + sbase + (size_t)cc * 4096 + tid * 8;
            u16* p1 = p0 + 2048;
            u16 t0v[8], t1v[8], o0[8], o1[8];
            *(uint4*)t0v = *(const uint4*)p0;
            *(uint4*)t1v = *(const uint4*)p1;
            #pragma unroll
            for (int q = 0; q < 8; ++q) {
                o0[q] = f2bf(r0[q]); r0[q] += bf2f(t0v[q]);
                o1[q] = f2bf(r1[q]); r1[q] += bf2f(t1v[q]);
            }
            *(uint4*)p0 = *(uint4*)o0;
            *(uint4*)p1 = *(uint4*)o1;
        }
        if (tid < 64) {
            const size_t zb = (size_t)bh * NCH * 64;
            float rz = 0.f;
            for (int cc = 0; cc < NCH; ++cc) {
                float tv = zloc[zb + cc * 64 + tid];
                zloc[zb + cc * 64 + tid] = rz;
                rz += tv;
            }
        }
    }
}

// ---------------------------------------------------------------------------
// attn (MFMA): y = (Q*Sp^T + causal(QK^T)*V) / (q.zp + rowsum + eps), bf16 out.
// All four operand tiles staged ASYNC into unpadded XOR-swizzled LDS
// (Q,K from qkv; Sp from scanned Spt; V^T from VtG). 1024 blocks, 4 waves.
// ---------------------------------------------------------------------------
__global__ __launch_bounds__(256) void attn_mfma_k(
    const u16* __restrict__ qkv,
    const u16* __restrict__ SptG,
    const float* __restrict__ zp,
    const u16* __restrict__ VtG,
    u16* __restrict__ Yb)
{
    __shared__ u16 Qls[64 * 64];   // Q [t][d] swizzled; reused as Y staging (plain)
    __shared__ u16 Kls[64 * 64];   // K [s][d] swizzled
    __shared__ u16 Vls[64 * 64];   // V^T [j][s] swizzled
    __shared__ u16 Sls[64 * 64];   // Sp^T [j][d] swizzled; then masked A [t][s]
    __shared__ float zps[64];
    __shared__ float den4[64][4];
    __shared__ float den[64];

    const int tid  = threadIdx.x;
    const int wave = tid >> 6, lane = tid & 63;
    const int quad = lane >> 4, lrow = lane & 15;
    const int blk = blockIdx.x;
    const int c = blk & 31, h = (blk >> 5) & 15, b = blk >> 9;
    const int t0 = c * 64;
    const int lr = lane >> 3;
    const int lc = ((lane & 7) ^ lr) * 8;
    const int rsw = lrow & 7;
    const u16* qbase = qkv + (size_t)(b * TB + t0) * 3072 + h * 64;

    #pragma unroll
    for (int m = 0; m < 2; ++m) {
        int i = wave * 2 + m;          // 8-row group 0..7
        int r = i * 8 + lr;
        async_load16(qbase + (size_t)r * 3072 + lc,          &Qls[i * 512]);
        async_load16(qbase + (size_t)r * 3072 + 1024 + lc,   &Kls[i * 512]);
        async_load16(SptG + (size_t)blk * 4096 + r * 64 + lc, &Sls[i * 512]);
        async_load16(VtG  + (size_t)blk * 4096 + r * 64 + lc, &Vls[i * 512]);
    }
    if (tid < 64) zps[tid] = zp[(size_t)blk * 64 + tid];
    __syncthreads();

    frag8 qf[2];
    #pragma unroll
    for (int ks = 0; ks < 2; ++ks)
        qf[ks] = *(const frag8*)&Qls[(wave * 16 + lrow) * 64 + ((ks * 4 + quad) ^ rsw) * 8];

    floatx4 yacc[4] = {}, kacc[4] = {};
    #pragma unroll
    for (int jn = 0; jn < 4; ++jn) {
        #pragma unroll
        for (int ks = 0; ks < 2; ++ks) {
            frag8 spf = *(const frag8*)&Sls[(jn * 16 + lrow) * 64 + ((ks * 4 + quad) ^ rsw) * 8];
            yacc[jn] = __builtin_amdgcn_mfma_f32_16x16x32_bf16(qf[ks], spf, yacc[jn], 0, 0, 0);
            frag8 kf = *(const frag8*)&Kls[(jn * 16 + lrow) * 64 + ((ks * 4 + quad) ^ rsw) * 8];
            kacc[jn] = __builtin_amdgcn_mfma_f32_16x16x32_bf16(qf[ks], kf, kacc[jn], 0, 0, 0);
        }
    }
    __syncthreads();   // done reading Sls; reuse for masked A (swizzled [t][s])

    #pragma unroll
    for (int jn = 0; jn < 4; ++jn) {
        int s = jn * 16 + lrow;
        #pragma unroll
        for (int r = 0; r < 4; ++r) {
            int t = wave * 16 + quad * 4 + r;
            float v = (s <= t) ? kacc[jn][r] : 0.f;
            Sls[t * 64 + (((s >> 3) ^ (t & 7)) * 8) + (s & 7)] = f2bf(v);
        }
    }
    __syncthreads();

    // den partials: den[t] = sum_d Q[t][d]*zp[d] + sum_s A[t][s]  (swizzle-aware)
    {
        int t = tid >> 2, seg = tid & 3;
        float p = 0.f;
        #pragma unroll
        for (int g2 = 0; g2 < 2; ++g2) {
            int g = seg * 2 + g2;
            int pq = ((g ^ (t & 7)) * 8);
            const u16* qp = &Qls[t * 64 + pq];
            const u16* ap = &Sls[t * 64 + pq];
            #pragma unroll
            for (int e = 0; e < 8; ++e) {
                p += bf2f(qp[e]) * zps[g * 8 + e] + bf2f(ap[e]);
            }
        }
        den4[t][seg] = p;
    }

    // y += A @ V
    frag8 af2[2];
    #pragma unroll
    for (int ks = 0; ks < 2; ++ks)
        af2[ks] = *(const frag8*)&Sls[(wave * 16 + lrow) * 64 + ((ks * 4 + quad) ^ rsw) * 8];
    #pragma unroll
    for (int jn = 0; jn < 4; ++jn)
        #pragma unroll
        for (int ks = 0; ks < 2; ++ks) {
            frag8 vf = *(const frag8*)&Vls[(jn * 16 + lrow) * 64 + ((ks * 4 + quad) ^ rsw) * 8];
            yacc[jn] = __builtin_amdgcn_mfma_f32_16x16x32_bf16(af2[ks], vf, yacc[jn], 0, 0, 0);
        }
    __syncthreads();
    if (tid < 64) den[tid] = den4[tid][0] + den4[tid][1] + den4[tid][2] + den4[tid][3];
    __syncthreads();

    // epilogue: normalize, stage into Qls (plain layout), vectorized store
    #pragma unroll
    for (int jn = 0; jn < 4; ++jn) {
        #pragma unroll
        for (int r = 0; r < 4; ++r) {
            int t = wave * 16 + quad * 4 + r;
            float inv = 1.f / (den[t] + EPSF);
            Qls[t * 64 + jn * 16 + lrow] = f2bf(yacc[jn][r] * inv);
        }
    }
    __syncthreads();
    {
        int row = tid >> 2, seg = tid & 3;
        size_t o = (size_t)(b * TB + t0 + row) * CCH + h * 64 + seg * 16;
        *(uint4*)(Yb + o)     = *(uint4*)&Qls[row * 64 + seg * 16];
        *(uint4*)(Yb + o + 8) = *(uint4*)&Qls[row * 64 + seg * 16 + 8];
    }
}

// ---------------------------------------------------------------------------
extern "C" void kernel_launch(void* const* d_in, const int* in_sizes, int n_in,
                              void* d_out, int out_size, void* d_ws, size_t ws_size,
                              hipStream_t stream)
{
    const float* x      = (const float*)d_in[0]; // (2,2048,1024) fp32
    const float* w_attn = (const float*)d_in[1]; // (1024,3072)   fp32
    const float* w_proj = (const float*)d_in[2]; // (1024,1024)   fp32
    float* out = (float*)d_out;                  // (2,2048,1024) fp32

    // Workspace layout:
    //   xb    : 4096*1024 bf16  (8 MB)
    //   waT   : 3072*1024 bf16  (6 MB)
    //   wpT   : 1024*1024 bf16  (2 MB)
    //   Yb    : 4096*1024 bf16  (8 MB)
    //   qkv_b : 4096*3072 bf16  (24 MB)
    //   Spt   : 1024*4096 bf16  (8 MB)   S_c then (in-place, ticket-scanned) S_pref
    //   VtG   : 1024*4096 bf16  (8 MB)   V^T per chunk (for attn async staging)
    //   zloc  : 1024*64   fp32  (0.25 MB)
    //   tickets: 32 u32 (zeroed per call)
    u16* xb    = (u16*)d_ws;
    u16* waT   = xb    + (size_t)4096 * 1024;
    u16* wpT   = waT   + (size_t)3072 * 1024;
    u16* Yb    = wpT   + (size_t)1024 * 1024;
    u16* qkv_b = Yb    + (size_t)4096 * 1024;
    u16* Spt   = qkv_b + (size_t)4096 * 3072;
    u16* VtG   = Spt   + (size_t)1024 * 4096;
    float* zloc = (float*)(VtG + (size_t)1024 * 4096);
    unsigned int* tickets = (unsigned int*)(zloc + (size_t)1024 * 64);

    hipMemsetAsync(tickets, 0, 32 * sizeof(unsigned int), stream);

    // Prep (fused): cvt x, transpose w_attn, transpose w_proj
    prep_k<<<3072, 256, 0, stream>>>(x, w_attn, w_proj, xb, waT, wpT);

    // GEMM1: qkv(bf16) = phi(x @ w_attn) (phi on q,k thirds: cols < 2048)
    gemm_bf16_bf16out_k<<<dim3(24, 32), 256, 0, stream>>>(xb, waT, qkv_b, 3072, 1024, 2048);

    // chunk states + ticket-fused prefix scan
    chunk_kv_mfma_k<<<1024, 256, 0, stream>>>(qkv_b, Spt, zloc, VtG, tickets);

    // attention output (fully async staging)
    attn_mfma_k<<<1024, 256, 0, stream>>>(qkv_b, Spt, zloc, VtG, Yb);

    // GEMM2: out = Y @ w_proj (128x64 tiles, BK=128 -> 512 blocks)
    gemm_bf16_f32out_k<<<dim3(16, 32), 256, 0, stream>>>(Yb, wpT, out, 1024, 1024);
}

// Round 14
// 169.203 us; speedup vs baseline: 1.8901x; 1.8901x over previous
//
#include <hip/hip_runtime.h>
#include <hip/hip_bf16.h>
#include <cmath>

// Problem dims (fixed by reference): B=2, T=2048, C=1024, H=16, D=64
// Inputs fp32, output fp32.
#define TB   2048
#define CCH  1024
#define NCH  32      // chunks per (b,h): T / 64
#define EPSF 1e-6f

typedef unsigned short u16;
typedef __attribute__((ext_vector_type(8))) short  frag8;   // 8 bf16 (4 VGPRs)
typedef __attribute__((ext_vector_type(4))) float  floatx4; // MFMA C/D

// RNE float -> bf16 (finite inputs only)
__device__ __forceinline__ u16 f2bf(float f) {
    unsigned int u = __float_as_uint(f);
    unsigned int r = (u + 0x7fffu + ((u >> 16) & 1u)) >> 16;
    return (u16)r;
}
__device__ __forceinline__ float bf2f(u16 v) {
    return __uint_as_float(((unsigned int)v) << 16);
}

// Async global->LDS, 16 B per lane (wave-uniform base + lane*16; unpadded dest).
__device__ __forceinline__ void async_load16(const u16* g, u16* l) {
    __builtin_amdgcn_global_load_lds(
        (const __attribute__((address_space(1))) void*)g,
        (__attribute__((address_space(3))) void*)l,
        16, 0, 0);
}

// ---------------------------------------------------------------------------
// Fused prep: [0,2048) cvt x->bf16 ; [2048,2816) transpose w_attn ; rest w_proj.
// ---------------------------------------------------------------------------
__global__ __launch_bounds__(256) void prep_k(
    const float* __restrict__ x, const float* __restrict__ wa,
    const float* __restrict__ wp,
    u16* __restrict__ xb, u16* __restrict__ waT, u16* __restrict__ wpT)
{
    __shared__ u16 t[64][72];   // t[n][k]
    int blk = blockIdx.x;
    if (blk < 2048) {                       // cvt: 4096*1024 elems, 8/thread
        int i = (blk * 256 + threadIdx.x) * 8;
        float4 a = *(const float4*)(x + i);
        float4 b = *(const float4*)(x + i + 4);
        u16 v[8];
        v[0] = f2bf(a.x); v[1] = f2bf(a.y); v[2] = f2bf(a.z); v[3] = f2bf(a.w);
        v[4] = f2bf(b.x); v[5] = f2bf(b.y); v[6] = f2bf(b.z); v[7] = f2bf(b.w);
        *(uint4*)(xb + i) = *(uint4*)v;
        return;
    }
    const float* in; u16* out; int K, N, bx, by;
    if (blk < 2048 + 768) {                 // w_attn^T: (1024 x 3072) -> (3072 x 1024)
        int tb = blk - 2048; in = wa; out = waT; K = 1024; N = 3072;
        bx = tb % 48; by = tb / 48;
    } else {                                // w_proj^T: (1024 x 1024)
        int tb = blk - 2816; in = wp; out = wpT; K = 1024; N = 1024;
        bx = tb & 15; by = tb >> 4;
    }
    const int k0 = by * 64, n0 = bx * 64;
    #pragma unroll
    for (int i = 0; i < 4; ++i) {
        int rr = (threadIdx.x >> 4) + 16 * i;          // k-row
        int c4 = (threadIdx.x & 15) * 4;               // n-col
        float4 v = *(const float4*)(in + (size_t)(k0 + rr) * N + n0 + c4);
        t[c4 + 0][rr] = f2bf(v.x);
        t[c4 + 1][rr] = f2bf(v.y);
        t[c4 + 2][rr] = f2bf(v.z);
        t[c4 + 3][rr] = f2bf(v.w);
    }
    __syncthreads();
    #pragma unroll
    for (int i = 0; i < 2; ++i) {
        int rr = (threadIdx.x >> 3) + 32 * i;          // n-row
        int c8 = (threadIdx.x & 7) * 8;                // k-chunk
        u16 o[8];
        #pragma unroll
        for (int q = 0; q < 8; ++q) o[q] = t[rr][c8 + q];
        *(uint4*)(out + (size_t)(n0 + rr) * K + k0 + c8) = *(uint4*)o;
    }
}

// ---------------------------------------------------------------------------
// GEMM1: qkv(bf16) = phi(x @ w_attn), phi on cols < phi_cols.
// m97 pattern + XOR chunk swizzle (verified conflict-free, round 8).
// ---------------------------------------------------------------------------
__global__ __launch_bounds__(256) void gemm_bf16_bf16out_k(
    const u16* __restrict__ A, const u16* __restrict__ BT,
    u16* __restrict__ C, int N, int K, int phi_cols)
{
    __shared__ u16 Als[128 * 64];
    __shared__ u16 Bls[128 * 64];
    const int tid  = threadIdx.x;
    const int wave = tid >> 6, lane = tid & 63;
    const int quad = lane >> 4, lrow = lane & 15;
    const int wm = wave >> 1, wn = wave & 1;
    const int row0 = blockIdx.y * 128, col0 = blockIdx.x * 128;
    const int lr = lane >> 3;
    const int lc = ((lane & 7) ^ lr) * 8;
    const int rsw = lrow & 7;
    floatx4 acc[4][4] = {};

    for (int k0 = 0; k0 < K; k0 += 64) {
        __syncthreads();
        #pragma unroll
        for (int m = 0; m < 4; ++m) {
            int i = wave * 4 + m;
            async_load16(A  + (size_t)(row0 + i * 8 + lr) * K + k0 + lc, &Als[i * 512]);
            async_load16(BT + (size_t)(col0 + i * 8 + lr) * K + k0 + lc, &Bls[i * 512]);
        }
        __syncthreads();
        #pragma unroll
        for (int ksi = 0; ksi < 2; ++ksi) {
            frag8 af[4], bf[4];
            #pragma unroll
            for (int i = 0; i < 4; ++i)
                af[i] = *(const frag8*)&Als[(wm * 64 + i * 16 + lrow) * 64
                                            + ((ksi * 4 + quad) ^ rsw) * 8];
            #pragma unroll
            for (int i = 0; i < 4; ++i)
                bf[i] = *(const frag8*)&Bls[(wn * 64 + i * 16 + lrow) * 64
                                            + ((ksi * 4 + quad) ^ rsw) * 8];
            #pragma unroll
            for (int i = 0; i < 4; ++i)
                #pragma unroll
                for (int jn = 0; jn < 4; ++jn)
                    acc[i][jn] = __builtin_amdgcn_mfma_f32_16x16x32_bf16(
                        af[i], bf[jn], acc[i][jn], 0, 0, 0);
        }
    }

    #pragma unroll
    for (int i = 0; i < 4; ++i) {
        #pragma unroll
        for (int jn = 0; jn < 4; ++jn) {
            int col = col0 + wn * 64 + jn * 16 + lrow;
            bool isphi = col < phi_cols;
            #pragma unroll
            for (int r = 0; r < 4; ++r) {
                int row = row0 + wm * 64 + i * 16 + quad * 4 + r;
                float v = acc[i][jn][r];
                if (isphi) v = (v > 0.f) ? (v + 1.f) : __expf(v);  // phi = elu+1
                C[(size_t)row * N + col] = f2bf(v);
            }
        }
    }
}

// ---------------------------------------------------------------------------
// GEMM2: out(fp32) = Y @ w_proj. 128x64 tile, BK=128, 16-chunk XOR swizzle.
// ---------------------------------------------------------------------------
__global__ __launch_bounds__(256) void gemm_bf16_f32out_k(
    const u16* __restrict__ A, const u16* __restrict__ BT,
    float* __restrict__ C, int N, int K)
{
    __shared__ u16 Als[128 * 128];
    __shared__ u16 Bls[64 * 128];
    const int tid  = threadIdx.x;
    const int wave = tid >> 6, lane = tid & 63;
    const int quad = lane >> 4, lrow = lane & 15;
    const int wm = wave >> 1, wn = wave & 1;
    const int row0 = blockIdx.y * 128, col0 = blockIdx.x * 64;
    const int lr4 = lane >> 4;
    floatx4 acc[4][2] = {};

    for (int k0 = 0; k0 < K; k0 += 128) {
        __syncthreads();
        #pragma unroll
        for (int m = 0; m < 8; ++m) {
            int rbase = wave * 32 + m * 4;
            int cg = (lane & 15) ^ ((rbase + lr4) & 15);
            async_load16(A + (size_t)(row0 + rbase + lr4) * K + k0 + cg * 8,
                         &Als[rbase * 128]);
        }
        #pragma unroll
        for (int m = 0; m < 4; ++m) {
            int rbase = wave * 16 + m * 4;
            int cg = (lane & 15) ^ ((rbase + lr4) & 15);
            async_load16(BT + (size_t)(col0 + rbase + lr4) * K + k0 + cg * 8,
                         &Bls[rbase * 128]);
        }
        __syncthreads();
        #pragma unroll
        for (int ksi = 0; ksi < 4; ++ksi) {
            frag8 af[4], bf[2];
            #pragma unroll
            for (int i = 0; i < 4; ++i)
                af[i] = *(const frag8*)&Als[(wm * 64 + i * 16 + lrow) * 128
                                            + ((ksi * 4 + quad) ^ lrow) * 8];
            #pragma unroll
            for (int jn = 0; jn < 2; ++jn)
                bf[jn] = *(const frag8*)&Bls[(wn * 32 + jn * 16 + lrow) * 128
                                             + ((ksi * 4 + quad) ^ lrow) * 8];
            #pragma unroll
            for (int i = 0; i < 4; ++i)
                #pragma unroll
                for (int jn = 0; jn < 2; ++jn)
                    acc[i][jn] = __builtin_amdgcn_mfma_f32_16x16x32_bf16(
                        af[i], bf[jn], acc[i][jn], 0, 0, 0);
        }
    }

    #pragma unroll
    for (int i = 0; i < 4; ++i)
        #pragma unroll
        for (int jn = 0; jn < 2; ++jn) {
            int col = col0 + wn * 32 + jn * 16 + lrow;
            #pragma unroll
            for (int r = 0; r < 4; ++r) {
                int row = row0 + wm * 64 + i * 16 + quad * 4 + r;
                C[(size_t)row * N + col] = acc[i][jn][r];
            }
        }
}

// ---------------------------------------------------------------------------
// chunk_kv (MFMA): S_c^T = V^T K (bf16 [j][i]); z_c = colsum K; V^T exported
// to VtG (plain stores, no fences) for attn's async staging.
// Grid 1024 blocks ((b*16+h)*32+c), 256 threads = 4 waves.
// ---------------------------------------------------------------------------
__global__ __launch_bounds__(256) void chunk_kv_mfma_k(
    const u16* __restrict__ qkv,
    u16* __restrict__ Spt,
    float* __restrict__ zloc,
    u16* __restrict__ VtG)
{
    __shared__ u16 Kt[64][72];   // K^T [d][s]
    __shared__ u16 Vt[64][72];   // V^T [j][s]
    const int tid  = threadIdx.x;
    const int wave = tid >> 6, lane = tid & 63;
    const int quad = lane >> 4, lrow = lane & 15;
    const int blk = blockIdx.x;
    const int c = blk & 31, h = (blk >> 5) & 15, b = blk >> 9;
    const int t0 = c * 64;
    const u16* base = qkv + (size_t)(b * TB + t0) * 3072 + h * 64;

    #pragma unroll
    for (int m = 0; m < 2; ++m) {
        int chunk = tid + 256 * m;
        int s = chunk >> 3, d0 = (chunk & 7) * 8;
        const u16* row = base + (size_t)s * 3072;
        u16 kv[8], vv[8];
        *(uint4*)kv = *(const uint4*)(row + 1024 + d0);
        *(uint4*)vv = *(const uint4*)(row + 2048 + d0);
        #pragma unroll
        for (int q = 0; q < 8; ++q) { Kt[d0 + q][s] = kv[q]; Vt[d0 + q][s] = vv[q]; }
    }
    __syncthreads();

    // export V^T (row-major [j][s]) for attn's async staging
    #pragma unroll
    for (int m = 0; m < 2; ++m) {
        int e = tid + 256 * m;
        int r = e >> 3, c8 = (e & 7) * 8;
        u16 o[8];
        #pragma unroll
        for (int q = 0; q < 8; ++q) o[q] = Vt[r][c8 + q];
        *(uint4*)(VtG + (size_t)blk * 4096 + r * 64 + c8) = *(uint4*)o;
    }

    frag8 vf[2];
    #pragma unroll
    for (int ks = 0; ks < 2; ++ks)
        vf[ks] = *(const frag8*)&Vt[wave * 16 + lrow][ks * 32 + quad * 8];
    u16* So = Spt + (size_t)blk * 4096;
    #pragma unroll
    for (int jn = 0; jn < 4; ++jn) {
        floatx4 acc = {};
        #pragma unroll
        for (int ks = 0; ks < 2; ++ks) {
            frag8 kf = *(const frag8*)&Kt[jn * 16 + lrow][ks * 32 + quad * 8];
            acc = __builtin_amdgcn_mfma_f32_16x16x32_bf16(vf[ks], kf, acc, 0, 0, 0);
        }
        #pragma unroll
        for (int r = 0; r < 4; ++r) {
            int j = wave * 16 + quad * 4 + r;     // row of S^T
            int i = jn * 16 + lrow;               // col of S^T
            So[j * 64 + i] = f2bf(acc[r]);
        }
    }
    if (tid < 64) {
        float z = 0.f;
        for (int s = 0; s < 64; ++s) z += bf2f(Kt[tid][s]);
        zloc[(size_t)blk * 64 + tid] = z;
    }
}

// ---------------------------------------------------------------------------
// Exclusive prefix over chunk axis, IN-PLACE on bf16 Spt, VECTORIZED:
// each thread owns 8 consecutive bf16 (uint4). Grid: 32 bh x 2 parts = 64.
// ---------------------------------------------------------------------------
__global__ __launch_bounds__(256) void scan_state_k(
    u16* __restrict__ Spt, float* __restrict__ z)
{
    const int bh = blockIdx.x >> 1;
    const int part = blockIdx.x & 1;
    const int e0 = part * 2048 + threadIdx.x * 8;
    const size_t base = (size_t)bh * NCH * 4096;
    float r[8] = {};
    for (int c = 0; c < NCH; ++c) {
        u16* p = Spt + base + (size_t)c * 4096 + e0;
        u16 t[8];
        *(uint4*)t = *(const uint4*)p;
        u16 o[8];
        #pragma unroll
        for (int q = 0; q < 8; ++q) { o[q] = f2bf(r[q]); r[q] += bf2f(t[q]); }
        *(uint4*)p = *(uint4*)o;
    }
    if (part == 0 && threadIdx.x < 64) {
        const size_t zb = (size_t)bh * NCH * 64;
        float rz = 0.f;
        for (int c = 0; c < NCH; ++c) {
            float t = z[zb + c * 64 + threadIdx.x];
            z[zb + c * 64 + threadIdx.x] = rz;
            rz += t;
        }
    }
}

// ---------------------------------------------------------------------------
// attn (MFMA): y = (Q*Sp^T + causal(QK^T)*V) / (q.zp + rowsum + eps), bf16 out.
// All four operand tiles staged ASYNC into unpadded XOR-swizzled LDS
// (Q,K from qkv; Sp from scanned Spt; V^T from VtG). 1024 blocks, 4 waves.
// Correctness-verified in round 13 (passed, absmax 0.0078125).
// ---------------------------------------------------------------------------
__global__ __launch_bounds__(256) void attn_mfma_k(
    const u16* __restrict__ qkv,
    const u16* __restrict__ SptG,
    const float* __restrict__ zp,
    const u16* __restrict__ VtG,
    u16* __restrict__ Yb)
{
    __shared__ u16 Qls[64 * 64];   // Q [t][d] swizzled; reused as Y staging (plain)
    __shared__ u16 Kls[64 * 64];   // K [s][d] swizzled
    __shared__ u16 Vls[64 * 64];   // V^T [j][s] swizzled
    __shared__ u16 Sls[64 * 64];   // Sp^T [j][d] swizzled; then masked A [t][s]
    __shared__ float zps[64];
    __shared__ float den4[64][4];
    __shared__ float den[64];

    const int tid  = threadIdx.x;
    const int wave = tid >> 6, lane = tid & 63;
    const int quad = lane >> 4, lrow = lane & 15;
    const int blk = blockIdx.x;
    const int c = blk & 31, h = (blk >> 5) & 15, b = blk >> 9;
    const int t0 = c * 64;
    const int lr = lane >> 3;
    const int lc = ((lane & 7) ^ lr) * 8;
    const int rsw = lrow & 7;
    const u16* qbase = qkv + (size_t)(b * TB + t0) * 3072 + h * 64;

    #pragma unroll
    for (int m = 0; m < 2; ++m) {
        int i = wave * 2 + m;          // 8-row group 0..7
        int r = i * 8 + lr;
        async_load16(qbase + (size_t)r * 3072 + lc,          &Qls[i * 512]);
        async_load16(qbase + (size_t)r * 3072 + 1024 + lc,   &Kls[i * 512]);
        async_load16(SptG + (size_t)blk * 4096 + r * 64 + lc, &Sls[i * 512]);
        async_load16(VtG  + (size_t)blk * 4096 + r * 64 + lc, &Vls[i * 512]);
    }
    if (tid < 64) zps[tid] = zp[(size_t)blk * 64 + tid];
    __syncthreads();

    frag8 qf[2];
    #pragma unroll
    for (int ks = 0; ks < 2; ++ks)
        qf[ks] = *(const frag8*)&Qls[(wave * 16 + lrow) * 64 + ((ks * 4 + quad) ^ rsw) * 8];

    floatx4 yacc[4] = {}, kacc[4] = {};
    #pragma unroll
    for (int jn = 0; jn < 4; ++jn) {
        #pragma unroll
        for (int ks = 0; ks < 2; ++ks) {
            frag8 spf = *(const frag8*)&Sls[(jn * 16 + lrow) * 64 + ((ks * 4 + quad) ^ rsw) * 8];
            yacc[jn] = __builtin_amdgcn_mfma_f32_16x16x32_bf16(qf[ks], spf, yacc[jn], 0, 0, 0);
            frag8 kf = *(const frag8*)&Kls[(jn * 16 + lrow) * 64 + ((ks * 4 + quad) ^ rsw) * 8];
            kacc[jn] = __builtin_amdgcn_mfma_f32_16x16x32_bf16(qf[ks], kf, kacc[jn], 0, 0, 0);
        }
    }
    __syncthreads();   // done reading Sls; reuse for masked A (swizzled [t][s])

    #pragma unroll
    for (int jn = 0; jn < 4; ++jn) {
        int s = jn * 16 + lrow;
        #pragma unroll
        for (int r = 0; r < 4; ++r) {
            int t = wave * 16 + quad * 4 + r;
            float v = (s <= t) ? kacc[jn][r] : 0.f;
            Sls[t * 64 + (((s >> 3) ^ (t & 7)) * 8) + (s & 7)] = f2bf(v);
        }
    }
    __syncthreads();

    // den partials: den[t] = sum_d Q[t][d]*zp[d] + sum_s A[t][s]  (swizzle-aware)
    {
        int t = tid >> 2, seg = tid & 3;
        float p = 0.f;
        #pragma unroll
        for (int g2 = 0; g2 < 2; ++g2) {
            int g = seg * 2 + g2;
            int pq = ((g ^ (t & 7)) * 8);
            const u16* qp = &Qls[t * 64 + pq];
            const u16* ap = &Sls[t * 64 + pq];
            #pragma unroll
            for (int e = 0; e < 8; ++e) {
                p += bf2f(qp[e]) * zps[g * 8 + e] + bf2f(ap[e]);
            }
        }
        den4[t][seg] = p;
    }

    // y += A @ V
    frag8 af2[2];
    #pragma unroll
    for (int ks = 0; ks < 2; ++ks)
        af2[ks] = *(const frag8*)&Sls[(wave * 16 + lrow) * 64 + ((ks * 4 + quad) ^ rsw) * 8];
    #pragma unroll
    for (int jn = 0; jn < 4; ++jn)
        #pragma unroll
        for (int ks = 0; ks < 2; ++ks) {
            frag8 vf = *(const frag8*)&Vls[(jn * 16 + lrow) * 64 + ((ks * 4 + quad) ^ rsw) * 8];
            yacc[jn] = __builtin_amdgcn_mfma_f32_16x16x32_bf16(af2[ks], vf, yacc[jn], 0, 0, 0);
        }
    __syncthreads();
    if (tid < 64) den[tid] = den4[tid][0] + den4[tid][1] + den4[tid][2] + den4[tid][3];
    __syncthreads();

    // epilogue: normalize, stage into Qls (plain layout), vectorized store
    #pragma unroll
    for (int jn = 0; jn < 4; ++jn) {
        #pragma unroll
        for (int r = 0; r < 4; ++r) {
            int t = wave * 16 + quad * 4 + r;
            float inv = 1.f / (den[t] + EPSF);
            Qls[t * 64 + jn * 16 + lrow] = f2bf(yacc[jn][r] * inv);
        }
    }
    __syncthreads();
    {
        int row = tid >> 2, seg = tid & 3;
        size_t o = (size_t)(b * TB + t0 + row) * CCH + h * 64 + seg * 16;
        *(uint4*)(Yb + o)     = *(uint4*)&Qls[row * 64 + seg * 16];
        *(uint4*)(Yb + o + 8) = *(uint4*)&Qls[row * 64 + seg * 16 + 8];
    }
}

// ---------------------------------------------------------------------------
extern "C" void kernel_launch(void* const* d_in, const int* in_sizes, int n_in,
                              void* d_out, int out_size, void* d_ws, size_t ws_size,
                              hipStream_t stream)
{
    const float* x      = (const float*)d_in[0]; // (2,2048,1024) fp32
    const float* w_attn = (const float*)d_in[1]; // (1024,3072)   fp32
    const float* w_proj = (const float*)d_in[2]; // (1024,1024)   fp32
    float* out = (float*)d_out;                  // (2,2048,1024) fp32

    // Workspace layout:
    //   xb    : 4096*1024 bf16  (8 MB)
    //   waT   : 3072*1024 bf16  (6 MB)
    //   wpT   : 1024*1024 bf16  (2 MB)
    //   Yb    : 4096*1024 bf16  (8 MB)
    //   qkv_b : 4096*3072 bf16  (24 MB)
    //   Spt   : 1024*4096 bf16  (8 MB)   S_c then (in-place, scanned) S_pref
    //   VtG   : 1024*4096 bf16  (8 MB)   V^T per chunk (attn async staging)
    //   zloc  : 1024*64   fp32  (0.25 MB)
    u16* xb    = (u16*)d_ws;
    u16* waT   = xb    + (size_t)4096 * 1024;
    u16* wpT   = waT   + (size_t)3072 * 1024;
    u16* Yb    = wpT   + (size_t)1024 * 1024;
    u16* qkv_b = Yb    + (size_t)4096 * 1024;
    u16* Spt   = qkv_b + (size_t)4096 * 3072;
    u16* VtG   = Spt   + (size_t)1024 * 4096;
    float* zloc = (float*)(VtG + (size_t)1024 * 4096);

    // Prep (fused): cvt x, transpose w_attn, transpose w_proj
    prep_k<<<3072, 256, 0, stream>>>(x, w_attn, w_proj, xb, waT, wpT);

    // GEMM1: qkv(bf16) = phi(x @ w_attn) (phi on q,k thirds: cols < 2048)
    gemm_bf16_bf16out_k<<<dim3(24, 32), 256, 0, stream>>>(xb, waT, qkv_b, 3072, 1024, 2048);

    // Chunked causal linear attention
    chunk_kv_mfma_k<<<1024, 256, 0, stream>>>(qkv_b, Spt, zloc, VtG);
    scan_state_k   <<<64,   256, 0, stream>>>(Spt, zloc);
    attn_mfma_k    <<<1024, 256, 0, stream>>>(qkv_b, Spt, zloc, VtG, Yb);

    // GEMM2: out = Y @ w_proj (128x64 tiles, BK=128 -> 512 blocks)
    gemm_bf16_f32out_k<<<dim3(16, 32), 256, 0, stream>>>(Yb, wpT, out, 1024, 1024);
}